// Round 1
// baseline (105.915 us; speedup 1.0000x reference)
//
#include <hip/hip_runtime.h>

// HoughCriterion: gaussian center-splat target + focal loss + scalar reduce.
// Levels: h0 [8,80,128,128], h1 [8,80,64,64], h2 [8,80,32,32] (fp32)
// boxes [8,32,4] fp32 normalized cxcywh, labels [8,32] i32, image_sizes unused.
// ws layout (floats): [0,640) num_pos per (b*C+c), [640,1280) pos_loss sum,
//                     [1280,1920) neg_loss sum.

#define BATCH 8
#define NBOX 32
#define NCH 80
#define NPLANE (BATCH * NCH)   // 640

__global__ __launch_bounds__(256) void splat_focal_kernel(
    const float* __restrict__ h0, const float* __restrict__ h1,
    const float* __restrict__ h2,
    const float* __restrict__ boxes, const int* __restrict__ labels,
    float* __restrict__ acc)
{
    const int bid = blockIdx.x;
    const int tid = threadIdx.x;

    int plane, log2W, px_count, base_global, inpl_base;
    const float* heat;
    if (bid < 4 * NPLANE) {              // level 0: 128x128, 4 blocks/plane
        plane = bid >> 2;
        const int chunk = bid & 3;
        log2W = 7; heat = h0; px_count = 4096;
        inpl_base = chunk * 4096;
        base_global = plane * 16384 + inpl_base;
    } else if (bid < 5 * NPLANE) {       // level 1: 64x64, 1 block/plane
        plane = bid - 4 * NPLANE;
        log2W = 6; heat = h1; px_count = 4096;
        inpl_base = 0;
        base_global = plane * 4096;
    } else {                             // level 2: 32x32, 1 block/plane
        plane = bid - 5 * NPLANE;
        log2W = 5; heat = h2; px_count = 1024;
        inpl_base = 0;
        base_global = plane * 1024;
    }
    const int W = 1 << log2W;
    const int b = plane / NCH;
    const int c = plane - b * NCH;

    // --- collect boxes of this batch with label==c, precompute per-level params
    __shared__ int s_k;
    __shared__ int s_x[NBOX], s_y[NBOX], s_r[NBOX];
    __shared__ float s_i2[NBOX];
    if (tid == 0) s_k = 0;
    __syncthreads();
    if (tid < NBOX) {
        if (labels[b * NBOX + tid] == c) {
            const float* bx = boxes + (b * NBOX + tid) * 4;
            const float fW = (float)W;
            float cx = bx[0] * fW, cy = bx[1] * fW;
            float bw = bx[2] * fW, bh = bx[3] * fW;   // H == W
            int xi = (int)floorf(cx);
            int yi = (int)floorf(cy);
            int r = (int)floorf((bw + bh) * 0.25f);
            r = max(1, r);
            float sigma = (float)(2 * r + 1) * (1.0f / 6.0f);
            int j = atomicAdd(&s_k, 1);
            s_x[j] = xi; s_y[j] = yi; s_r[j] = r;
            s_i2[j] = 1.0f / (2.0f * sigma * sigma);
        }
    }
    __syncthreads();
    const int k = s_k;

    float np_ = 0.0f, pl_ = 0.0f, nl_ = 0.0f;
    const int nf4 = px_count >> 2;
    const float4* hp = (const float4*)(heat + base_global);

    for (int i = tid; i < nf4; i += 256) {
        float4 hq = hp[i];
        const int off = inpl_base + (i << 2);
        const int py = off >> log2W;
        const int px0 = off & (W - 1);

        float t0 = 0.0f, t1 = 0.0f, t2 = 0.0f, t3 = 0.0f;
        for (int j = 0; j < k; ++j) {
            const int xj = s_x[j], yj = s_y[j], rj = s_r[j];
            const float i2 = s_i2[j];
            const int dy = py - yj;
            if (dy < -rj || dy > rj) continue;
            const float fdy2 = (float)(dy * dy);
            int dx = px0 - xj;
            if (dx >= -rj && dx <= rj)
                t0 = fmaxf(t0, __expf(-((float)(dx * dx) + fdy2) * i2));
            dx += 1;
            if (dx >= -rj && dx <= rj)
                t1 = fmaxf(t1, __expf(-((float)(dx * dx) + fdy2) * i2));
            dx += 1;
            if (dx >= -rj && dx <= rj)
                t2 = fmaxf(t2, __expf(-((float)(dx * dx) + fdy2) * i2));
            dx += 1;
            if (dx >= -rj && dx <= rj)
                t3 = fmaxf(t3, __expf(-((float)(dx * dx) + fdy2) * i2));
        }

        const float hv[4] = {hq.x, hq.y, hq.z, hq.w};
        const float tv[4] = {t0, t1, t2, t3};
        #pragma unroll
        for (int j2 = 0; j2 < 4; ++j2) {
            float p = 1.0f / (1.0f + __expf(-hv[j2]));
            p = fminf(fmaxf(p, 1e-4f), 1.0f - 1e-4f);
            const float t = tv[j2];
            if (t == 1.0f) {
                const float omp = 1.0f - p;
                pl_ += __logf(p) * omp * omp;
                np_ += 1.0f;
            } else {
                const float omt = 1.0f - t;
                const float nw = (omt * omt) * (omt * omt);
                nl_ += __logf(1.0f - p) * p * p * nw;
            }
        }
    }

    // --- block reduce (wave64 shuffle, then cross-wave via LDS)
    for (int o = 32; o > 0; o >>= 1) {
        np_ += __shfl_down(np_, o, 64);
        pl_ += __shfl_down(pl_, o, 64);
        nl_ += __shfl_down(nl_, o, 64);
    }
    __shared__ float s_np[4], s_pl[4], s_nl[4];
    const int wave = tid >> 6, lane = tid & 63;
    if (lane == 0) { s_np[wave] = np_; s_pl[wave] = pl_; s_nl[wave] = nl_; }
    __syncthreads();
    if (tid == 0) {
        float a = s_np[0] + s_np[1] + s_np[2] + s_np[3];
        float ps = s_pl[0] + s_pl[1] + s_pl[2] + s_pl[3];
        float ns = s_nl[0] + s_nl[1] + s_nl[2] + s_nl[3];
        atomicAdd(&acc[plane], a);
        atomicAdd(&acc[NPLANE + plane], ps);
        atomicAdd(&acc[2 * NPLANE + plane], ns);
    }
}

__global__ __launch_bounds__(256) void finalize_kernel(
    const float* __restrict__ acc, float* __restrict__ out)
{
    const int tid = threadIdx.x;
    float s = 0.0f;
    for (int i = tid; i < NPLANE; i += 256) {
        const float np_ = acc[i];
        const float pl_ = acc[NPLANE + i];
        const float nl_ = acc[2 * NPLANE + i];
        float loss = (np_ == 0.0f) ? (-nl_) : (-(pl_ + nl_) / np_);
        s += fminf(loss, 10.0f);
    }
    for (int o = 32; o > 0; o >>= 1) s += __shfl_down(s, o, 64);
    __shared__ float sw[4];
    const int wave = tid >> 6, lane = tid & 63;
    if (lane == 0) sw[wave] = s;
    __syncthreads();
    if (tid == 0) {
        const float mean = (sw[0] + sw[1] + sw[2] + sw[3]) * (1.0f / (float)NPLANE);
        const float lm = log1pf(mean);
        out[0] = lm / (1.0f + lm);
    }
}

extern "C" void kernel_launch(void* const* d_in, const int* in_sizes, int n_in,
                              void* d_out, int out_size, void* d_ws, size_t ws_size,
                              hipStream_t stream) {
    const float* h0 = (const float*)d_in[0];
    const float* h1 = (const float*)d_in[1];
    const float* h2 = (const float*)d_in[2];
    const float* boxes = (const float*)d_in[3];
    const int* labels = (const int*)d_in[4];
    // d_in[5] image_sizes: unused (cancels in the reference math)

    float* acc = (float*)d_ws;
    hipMemsetAsync(acc, 0, 3 * NPLANE * sizeof(float), stream);

    // level0: 4 blocks/plane (2560), level1: 1/plane (640), level2: 1/plane (640)
    splat_focal_kernel<<<6 * NPLANE, 256, 0, stream>>>(h0, h1, h2, boxes, labels, acc);
    finalize_kernel<<<1, 256, 0, stream>>>(acc, (float*)d_out);
}

// Round 2
// 101.526 us; speedup vs baseline: 1.0432x; 1.0432x over previous
//
#include <hip/hip_runtime.h>

// HoughCriterion: gaussian center-splat target + focal loss + scalar reduce.
// h0 [8,80,128,128], h1 [8,80,64,64], h2 [8,80,32,32] fp32;
// boxes [8,32,4] fp32 cxcywh normalized; labels [8,32] i32; image_sizes unused.
//
// ws layout (floats): per-block partials, no init required (every slot written):
//   np[0..NBLK), pl[NBLK..2*NBLK), nl[2*NBLK..3*NBLK)
// Block->plane map: bid<2560: level0, plane=bid>>2 (4 blocks/plane);
//   2560..3199: level1, plane=bid-2560; 3200..3839: level2, plane=bid-3200.

#define BATCH 8
#define NBOX 32
#define NCH 80
#define NPLANE 640
#define NBLK 3840

__device__ __forceinline__ float sigmoid_clip(float h) {
    const float e = __expf(-h);
    float p = __builtin_amdgcn_rcpf(1.0f + e);     // v_rcp_f32, ~1 ulp
    return fminf(fmaxf(p, 1e-4f), 1.0f - 1e-4f);
}

__global__ __launch_bounds__(256) void splat_focal_kernel(
    const float* __restrict__ h0, const float* __restrict__ h1,
    const float* __restrict__ h2,
    const float* __restrict__ boxes, const int* __restrict__ labels,
    float* __restrict__ part)
{
    const int bid = blockIdx.x;
    const int tid = threadIdx.x;

    int plane, log2W, px_count, base_global, inpl_base;
    const float* heat;
    if (bid < 4 * NPLANE) {              // level 0: 128x128, 4 blocks/plane
        plane = bid >> 2;
        const int chunk = bid & 3;
        log2W = 7; heat = h0; px_count = 4096;
        inpl_base = chunk * 4096;
        base_global = plane * 16384 + inpl_base;
    } else if (bid < 5 * NPLANE) {       // level 1: 64x64
        plane = bid - 4 * NPLANE;
        log2W = 6; heat = h1; px_count = 4096;
        inpl_base = 0;
        base_global = plane * 4096;
    } else {                             // level 2: 32x32
        plane = bid - 5 * NPLANE;
        log2W = 5; heat = h2; px_count = 1024;
        inpl_base = 0;
        base_global = plane * 1024;
    }
    const int W = 1 << log2W;
    const int b = plane / NCH;
    const int c = plane - b * NCH;

    // --- collect boxes of this (batch, class); block-uniform result
    __shared__ int s_k;
    __shared__ int s_x[NBOX], s_y[NBOX], s_r[NBOX];
    __shared__ float s_i2[NBOX];
    if (tid == 0) s_k = 0;
    __syncthreads();
    if (tid < NBOX) {
        if (labels[b * NBOX + tid] == c) {
            const float* bx = boxes + (b * NBOX + tid) * 4;
            const float fW = (float)W;
            int xi = (int)floorf(bx[0] * fW);
            int yi = (int)floorf(bx[1] * fW);
            int r = max(1, (int)floorf((bx[2] + bx[3]) * fW * 0.25f));
            float sigma = (float)(2 * r + 1) * (1.0f / 6.0f);
            int j = atomicAdd(&s_k, 1);
            s_x[j] = xi; s_y[j] = yi; s_r[j] = r;
            s_i2[j] = 1.0f / (2.0f * sigma * sigma);
        }
    }
    __syncthreads();
    const int k = s_k;

    float np_ = 0.0f, pl_ = 0.0f, nl_ = 0.0f;
    const int nf4 = px_count >> 2;
    const float4* hp = (const float4*)(heat + base_global);

    if (k == 0) {
        // pure-negative fast path: t == 0 everywhere -> nw = 1, no pos test
        for (int i = tid; i < nf4; i += 256) {
            const float4 hq = hp[i];
            const float hv[4] = {hq.x, hq.y, hq.z, hq.w};
            #pragma unroll
            for (int j2 = 0; j2 < 4; ++j2) {
                const float p = sigmoid_clip(hv[j2]);
                nl_ += __logf(1.0f - p) * p * p;
            }
        }
    } else {
        for (int i = tid; i < nf4; i += 256) {
            const float4 hq = hp[i];
            const int off = inpl_base + (i << 2);
            const int py = off >> log2W;
            const int px0 = off & (W - 1);

            float t0 = 0.0f, t1 = 0.0f, t2 = 0.0f, t3 = 0.0f;
            for (int j = 0; j < k; ++j) {
                const int xj = s_x[j], yj = s_y[j], rj = s_r[j];
                const float i2 = s_i2[j];
                const int dy = py - yj;
                if (dy < -rj || dy > rj) continue;
                const float fdy2 = (float)(dy * dy);
                int dx = px0 - xj;
                if (dx >= -rj && dx <= rj)
                    t0 = fmaxf(t0, __expf(-((float)(dx * dx) + fdy2) * i2));
                dx += 1;
                if (dx >= -rj && dx <= rj)
                    t1 = fmaxf(t1, __expf(-((float)(dx * dx) + fdy2) * i2));
                dx += 1;
                if (dx >= -rj && dx <= rj)
                    t2 = fmaxf(t2, __expf(-((float)(dx * dx) + fdy2) * i2));
                dx += 1;
                if (dx >= -rj && dx <= rj)
                    t3 = fmaxf(t3, __expf(-((float)(dx * dx) + fdy2) * i2));
            }

            const float hv[4] = {hq.x, hq.y, hq.z, hq.w};
            const float tv[4] = {t0, t1, t2, t3};
            #pragma unroll
            for (int j2 = 0; j2 < 4; ++j2) {
                const float p = sigmoid_clip(hv[j2]);
                const float t = tv[j2];
                if (t == 1.0f) {
                    const float omp = 1.0f - p;
                    pl_ += __logf(p) * omp * omp;
                    np_ += 1.0f;
                } else {
                    const float omt = 1.0f - t;
                    const float nw = (omt * omt) * (omt * omt);
                    nl_ += __logf(1.0f - p) * p * p * nw;
                }
            }
        }
    }

    // --- block reduce: wave64 shuffle then cross-wave via LDS
    for (int o = 32; o > 0; o >>= 1) {
        np_ += __shfl_down(np_, o, 64);
        pl_ += __shfl_down(pl_, o, 64);
        nl_ += __shfl_down(nl_, o, 64);
    }
    __shared__ float s_np[4], s_pl[4], s_nl[4];
    const int wave = tid >> 6, lane = tid & 63;
    if (lane == 0) { s_np[wave] = np_; s_pl[wave] = pl_; s_nl[wave] = nl_; }
    __syncthreads();
    if (tid == 0) {
        part[bid]            = s_np[0] + s_np[1] + s_np[2] + s_np[3];
        part[NBLK + bid]     = s_pl[0] + s_pl[1] + s_pl[2] + s_pl[3];
        part[2 * NBLK + bid] = s_nl[0] + s_nl[1] + s_nl[2] + s_nl[3];
    }
}

__global__ __launch_bounds__(256) void finalize_kernel(
    const float* __restrict__ part, float* __restrict__ out)
{
    const int tid = threadIdx.x;
    const float* np = part;
    const float* pl = part + NBLK;
    const float* nl = part + 2 * NBLK;

    float s = 0.0f;
    for (int p = tid; p < NPLANE; p += 256) {
        const float4 n4 = ((const float4*)np)[p];   // level-0 blocks 4p..4p+3
        const float4 p4 = ((const float4*)pl)[p];
        const float4 l4 = ((const float4*)nl)[p];
        const float a  = n4.x + n4.y + n4.z + n4.w + np[2560 + p] + np[3200 + p];
        const float ps = p4.x + p4.y + p4.z + p4.w + pl[2560 + p] + pl[3200 + p];
        const float ns = l4.x + l4.y + l4.z + l4.w + nl[2560 + p] + nl[3200 + p];
        const float loss = (a == 0.0f) ? (-ns) : (-(ps + ns) / a);
        s += fminf(loss, 10.0f);
    }
    for (int o = 32; o > 0; o >>= 1) s += __shfl_down(s, o, 64);
    __shared__ float sw[4];
    const int wave = tid >> 6, lane = tid & 63;
    if (lane == 0) sw[wave] = s;
    __syncthreads();
    if (tid == 0) {
        const float mean = (sw[0] + sw[1] + sw[2] + sw[3]) * (1.0f / (float)NPLANE);
        const float lm = log1pf(mean);
        out[0] = lm / (1.0f + lm);
    }
}

extern "C" void kernel_launch(void* const* d_in, const int* in_sizes, int n_in,
                              void* d_out, int out_size, void* d_ws, size_t ws_size,
                              hipStream_t stream) {
    const float* h0 = (const float*)d_in[0];
    const float* h1 = (const float*)d_in[1];
    const float* h2 = (const float*)d_in[2];
    const float* boxes = (const float*)d_in[3];
    const int* labels = (const int*)d_in[4];
    // d_in[5] image_sizes: unused (cancels in reference math)

    float* part = (float*)d_ws;   // 3*NBLK floats, fully overwritten every call

    splat_focal_kernel<<<NBLK, 256, 0, stream>>>(h0, h1, h2, boxes, labels, part);
    finalize_kernel<<<1, 256, 0, stream>>>(part, (float*)d_out);
}